// Round 1
// baseline (411.795 us; speedup 1.0000x reference)
//
#include <hip/hip_runtime.h>

typedef float v4f __attribute__((ext_vector_type(4)));

#define BATCH 16384
#define NS    5
#define NCTX  10
#define XSTR  (NCTX + 2)
#define D4    75          // 300 floats = 75 float4; rows are 1200B -> 16B aligned
#define NBLK  2048        // 2048 blocks x 4 waves = 8192 waves; 2 rows per wave

// One wave per PAIR of batch rows. Lanes own float4 chunks: lane l owns chunk
// l, plus chunk 64+l for l < 11. All gather indices are wave-uniform, so they
// are moved to SGPRs via readlane -> scalar-base + shared-voffset addressing.
// Ws loads are PLAIN (not nontemporal): per-iteration working set is
// Wg 60MB + touched-Ws ~84MB < 256MB L3, and the bench replays identical
// inputs, so letting L3 retain Ws is strictly better than re-streaming it
// from HBM every iteration; duplicate head words (~16%) also hit in-cache.
__global__ __launch_bounds__(256) void sense_partials(
    const int*   __restrict__ x,
    const float* __restrict__ Wg,
    const float* __restrict__ Ws,
    float*       __restrict__ partial /* [NS][NBLK] */) {
  const int lane = threadIdx.x & 63;
  const int wid  = threadIdx.x >> 6;          // 4 waves per block
  const int pair = blockIdx.x * 4 + wid;      // 0..8191
  const int b0   = pair * 2;                  // rows b0, b0+1

  const v4f* Wg4 = (const v4f*)Wg;
  const v4f* Ws4 = (const v4f*)Ws;

  // both rows' x entries in one 24-lane load
  int vx = (lane < 2 * XSTR) ? x[(size_t)b0 * XSTR + lane] : 0;

  // wave-uniform indices -> SGPRs (readlane ignores exec, lanes 0..23 valid)
  const int wA = __builtin_amdgcn_readlane(vx, 0);
  const int wB = __builtin_amdgcn_readlane(vx, XSTR);

  const v4f* WsA = Ws4 + (size_t)wA * (NS * D4);
  const v4f* WsB = Ws4 + (size_t)wB * (NS * D4);

  const bool hi = (lane < D4 - 64);           // lanes 0..10 own chunk 64+lane

  v4f sA0 = 0.f, sA1 = 0.f, sB0 = 0.f, sB1 = 0.f;
#pragma unroll
  for (int j = 0; j < NCTX; ++j) {
    const int ca = __builtin_amdgcn_readlane(vx, 2 + j);
    const int cb = __builtin_amdgcn_readlane(vx, XSTR + 2 + j);
    const v4f* ra = Wg4 + (size_t)ca * D4;    // SGPR base, voffset = lane*16
    const v4f* rb = Wg4 + (size_t)cb * D4;
    sA0 += ra[lane];
    sB0 += rb[lane];
    if (hi) {
      sA1 += ra[64 + lane];
      sB1 += rb[64 + lane];
    }
  }

  // Issue ALL 20 Ws loads before any FMA consumes one: they ride out a single
  // vmcnt window and their HBM/L3 latency overlaps the tail of the Wg phase.
  v4f a0[NS], c0[NS], a1[NS], c1[NS];
#pragma unroll
  for (int s = 0; s < NS; ++s) {
    a0[s] = WsA[s * D4 + lane];
    c0[s] = WsB[s * D4 + lane];
    a1[s] = 0.f;
    c1[s] = 0.f;
  }
  if (hi) {
#pragma unroll
    for (int s = 0; s < NS; ++s) {
      a1[s] = WsA[s * D4 + 64 + lane];
      c1[s] = WsB[s * D4 + 64 + lane];
    }
  }

  float acc[NS];
#pragma unroll
  for (int s = 0; s < NS; ++s) {
    v4f p = a0[s] * sA0 + c0[s] * sB0;
    if (hi) p += a1[s] * sA1 + c1[s] * sB1;
    acc[s] = p.x + p.y + p.z + p.w;
  }

  // wave reduction (64 lanes)
#pragma unroll
  for (int s = 0; s < NS; ++s) {
    float t = acc[s];
#pragma unroll
    for (int off = 32; off; off >>= 1) t += __shfl_down(t, off);
    acc[s] = t;
  }

  __shared__ float red[4][NS];
  if (lane == 0) {
#pragma unroll
    for (int s = 0; s < NS; ++s) red[wid][s] = acc[s];
  }
  __syncthreads();
  if (threadIdx.x < NS) {
    float t = red[0][threadIdx.x] + red[1][threadIdx.x] +
              red[2][threadIdx.x] + red[3][threadIdx.x];
    partial[threadIdx.x * NBLK + blockIdx.x] = t;   // s-major for easy reduce
  }
}

// Kernel 2: 5 waves, wave s reduces partial[s][*], writes sigmoid.
__global__ __launch_bounds__(320) void sense_reduce(
    const float* __restrict__ partial, float* __restrict__ out) {
  const int lane = threadIdx.x & 63;
  const int s    = threadIdx.x >> 6;   // 0..4
  float sum = 0.f;
  for (int g = lane; g < NBLK; g += 64) sum += partial[s * NBLK + g];
#pragma unroll
  for (int off = 32; off; off >>= 1) sum += __shfl_down(sum, off);
  if (lane == 0) out[s] = 1.0f / (1.0f + __expf(-sum));
}

extern "C" void kernel_launch(void* const* d_in, const int* in_sizes, int n_in,
                              void* d_out, int out_size, void* d_ws, size_t ws_size,
                              hipStream_t stream) {
  const int*   x  = (const int*)d_in[0];
  const float* Wg = (const float*)d_in[1];
  const float* Ws = (const float*)d_in[2];
  float* partial  = (float*)d_ws;          // NS*NBLK*4 = 40 KB
  float* out      = (float*)d_out;

  sense_partials<<<NBLK, 256, 0, stream>>>(x, Wg, Ws, partial);
  sense_reduce<<<1, 320, 0, stream>>>(partial, out);
}